// Round 3
// baseline (412.046 us; speedup 1.0000x reference)
//
#include <hip/hip_runtime.h>
#include <cstdint>

#define HW 200704      // 448*448
#define IMG_W 448
#define NCLS 20
#define NDIM 256
#define CAPG 2560      // candidate cap per (b,c); mean 2007, sd 45 at T=0.99
#define TFILT 0.99f
#define LK 257         // padded LDS stride (257 mod 32 == 1 -> conflict-free)

// ---------------------------------------------------------------------------
// K0: coalesced transpose fmap [B,256,784] -> fmapT [B,784,256] via LDS tiles.
// grid = B * 8(dTiles) * 25(sTiles), block 256 = 8x32.
__global__ __launch_bounds__(256) void k_transpose(const float* __restrict__ fmap,
                                                   float* __restrict__ fmapT) {
  __shared__ float tile[32][33];
  int blk = blockIdx.x;
  int b = blk / 200;
  int t = blk % 200;
  int dT = t / 25, sT = t % 25;
  int ty = threadIdx.x >> 5;       // 0..7
  int tx = threadIdx.x & 31;       // 0..31
#pragma unroll
  for (int r = 0; r < 4; ++r) {
    int d = dT * 32 + ty + r * 8;
    int s = sT * 32 + tx;
    if (s < 784) tile[ty + r * 8][tx] = fmap[((size_t)(b * 256 + d)) * 784 + s];
  }
  __syncthreads();
#pragma unroll
  for (int r = 0; r < 4; ++r) {
    int s = sT * 32 + ty + r * 8;
    int d = dT * 32 + tx;
    if (s < 784) fmapT[((size_t)(b * 784 + s)) * 256 + d] = tile[tx][ty + r * 8];
  }
}

// ---------------------------------------------------------------------------
// K1: fused pseudo-label + bilinear weight scatter + top-k candidate filter.
// One float4-vectorized pass over cam, fixed 20-class unrolled loop (20
// independent dwordx4 loads in flight). grid = 2*196, 4 pixels/thread.
__global__ __launch_bounds__(256) void k_pseudo_filter(const float* __restrict__ cam,
                                                       const float* __restrict__ cls_label,
                                                       const float* __restrict__ hig_p,
                                                       const float* __restrict__ low_p,
                                                       const float* __restrict__ bg_p,
                                                       float* __restrict__ W,
                                                       int* __restrict__ counts,
                                                       int* __restrict__ candCnt,
                                                       float* __restrict__ candV,
                                                       int* __restrict__ candI) {
  int b = blockIdx.x / 196;
  int pix0 = (blockIdx.x % 196) * 1024 + threadIdx.x * 4;
  __shared__ float sLab[NCLS];
  if (threadIdx.x < NCLS) sLab[threadIdx.x] = cls_label[b * NCLS + threadIdx.x];
  __syncthreads();
  const float* camb = cam + (size_t)b * NCLS * HW;
  float top1[4]  = {-1.0f, -1.0f, -1.0f, -1.0f};
  float sec[4]   = {-1.0f, -1.0f, -1.0f, -1.0f};
  int   idx1[4]  = {0, 0, 0, 0};
#pragma unroll
  for (int c = 0; c < NCLS; ++c) {
    const float4 v4 = *(const float4*)(camb + (size_t)c * HW + pix0);
    float lab = sLab[c];
    float vv[4] = {v4.x * lab, v4.y * lab, v4.z * lab, v4.w * lab};
#pragma unroll
    for (int u = 0; u < 4; ++u) {
      float v = vv[u];
      // ascending c + strict '>' == lowest-index tie-break (JAX top_k)
      if (v > top1[u]) { sec[u] = top1[u]; top1[u] = v; idx1[u] = c; }
      else if (v > sec[u]) sec[u] = v;
      if (v >= TFILT) {              // rare (~1%): plain per-lane atomic
        int pos = atomicAdd(&candCnt[b * NCLS + c], 1);
        if (pos < CAPG) {
          candV[(size_t)(b * NCLS + c) * CAPG + pos] = v;
          candI[(size_t)(b * NCLS + c) * CAPG + pos] = pix0 + u;
        }
      }
    }
  }
  float hig = hig_p[0], low = low_p[0], bg = bg_p[0];
#pragma unroll
  for (int u = 0; u < 4; ++u) {
    int ps = idx1[u] + 1;
    float t1 = top1[u];
    if (t1 < hig) ps = 255;
    if (t1 < low) ps = 0;
    if (t1 < bg)  ps = 0;
    if ((t1 - sec[u] < 0.3f) && (t1 > hig)) ps = 255;
    if (ps >= 1 && ps <= NCLS) {
      int cls = ps - 1;
      int pix = pix0 + u;
      int y = pix / IMG_W, x = pix % IMG_W;
      float sy = (y + 0.5f) * 0.0625f - 0.5f; sy = fminf(fmaxf(sy, 0.0f), 27.0f);
      float sx = (x + 0.5f) * 0.0625f - 0.5f; sx = fminf(fmaxf(sx, 0.0f), 27.0f);
      int fy0 = (int)sy, fx0 = (int)sx;
      int fy1 = min(fy0 + 1, 27), fx1 = min(fx0 + 1, 27);
      float wy = sy - (float)fy0, wx = sx - (float)fx0;
      float* Wb = W + (size_t)(b * NCLS + cls) * 784;
      atomicAdd(&Wb[fy0 * 28 + fx0], (1.0f - wy) * (1.0f - wx));
      atomicAdd(&Wb[fy0 * 28 + fx1], (1.0f - wy) * wx);
      atomicAdd(&Wb[fy1 * 28 + fx0], wy * (1.0f - wx));
      atomicAdd(&Wb[fy1 * 28 + fx1], wy * wx);
      atomicAdd(&counts[b * NCLS + cls], 1);
    }
  }
}

// ---------------------------------------------------------------------------
// K2: exact top-25 per (b,c) — only runs for present classes with count==0
// (topIdx is only consumed on the counts==0 branch). grid = 40 blocks.
__global__ __launch_bounds__(256) void k_select(const float* __restrict__ cam,
                                                const float* __restrict__ cls_label,
                                                const int* __restrict__ counts,
                                                const int* __restrict__ candCnt,
                                                const float* __restrict__ candV,
                                                const int* __restrict__ candI,
                                                int* __restrict__ topIdx) {
  int bc = blockIdx.x;
  if (cls_label[bc] == 0.0f) return;     // fsm row is zeroed anyway
  if (counts[bc] > 0) return;            // feat_mask branch -> topIdx unused
  __shared__ float cv[CAPG]; __shared__ int ci[CAPG];
  __shared__ float wv[4]; __shared__ int wi[4];
  __shared__ float selV; __shared__ int selI;
  int tid = threadIdx.x;
  int n = candCnt[bc];
  bool fb = (n < 25) || (n > CAPG);      // exact fallback (never in practice)
  if (!fb) {
    for (int p = tid; p < n; p += 256) {
      cv[p] = candV[(size_t)bc * CAPG + p];
      ci[p] = candI[(size_t)bc * CAPG + p];
    }
  }
  __syncthreads();
  const float* camc = cam + (size_t)bc * HW;   // lab==1 -> valid_cam == cam
  float lastV = 3.0e38f; int lastI = -1;
  for (int r = 0; r < 25; ++r) {
    float bv = -1.0e30f; int bi = 0x7fffffff;
    if (!fb) {
      for (int p = tid; p < n; p += 256) {
        float v = cv[p]; int i = ci[p];
        if (((v < lastV) || (v == lastV && i > lastI)) &&
            ((v > bv) || (v == bv && i < bi))) { bv = v; bi = i; }
      }
    } else {
      for (int p = tid; p < HW; p += 256) {
        float v = camc[p];
        if (((v < lastV) || (v == lastV && p > lastI)) &&
            ((v > bv) || (v == bv && p < bi))) { bv = v; bi = p; }
      }
    }
    // wave-level argmax (value desc, index asc), no barriers
    for (int off = 32; off > 0; off >>= 1) {
      float ov = __shfl_xor(bv, off, 64);
      int   oi = __shfl_xor(bi, off, 64);
      if (ov > bv || (ov == bv && oi < bi)) { bv = ov; bi = oi; }
    }
    if ((tid & 63) == 0) { wv[tid >> 6] = bv; wi[tid >> 6] = bi; }
    __syncthreads();
    if (tid == 0) {
      for (int w = 1; w < 4; ++w)
        if (wv[w] > bv || (wv[w] == bv && wi[w] < bi)) { bv = wv[w]; bi = wi[w]; }
      selV = bv; selI = bi;
      topIdx[bc * 25 + r] = bi;
    }
    __syncthreads();
    lastV = selV; lastI = selI;
  }
}

// ---------------------------------------------------------------------------
// K3: per (b,c) feature row. cnt>0 -> W-dot only; cnt==0 -> 25 gathers only.
__global__ __launch_bounds__(256) void k_features(const float* __restrict__ fmapT,
                                                  const float* __restrict__ W,
                                                  const int* __restrict__ counts,
                                                  const int* __restrict__ topIdx,
                                                  const float* __restrict__ cls_label,
                                                  float* __restrict__ fsm_g) {
  int bc = blockIdx.x;
  int b = bc / NCLS;
  int tid = threadIdx.x;
  if (cls_label[bc] == 0.0f) { fsm_g[(size_t)bc * 256 + tid] = 0.0f; return; }
  int cnt = counts[bc];
  const float* fT = fmapT + (size_t)b * 784 * 256;
  float res;
  if (cnt > 0) {
    __shared__ float sW[784];
    for (int s = tid; s < 784; s += 256) sW[s] = W[(size_t)bc * 784 + s];
    __syncthreads();
    float a0 = 0.0f, a1 = 0.0f, a2 = 0.0f, a3 = 0.0f;
#pragma unroll 4
    for (int s = 0; s < 784; s += 4) {
      a0 += sW[s]     * fT[(size_t)(s)     * 256 + tid];
      a1 += sW[s + 1] * fT[(size_t)(s + 1) * 256 + tid];
      a2 += sW[s + 2] * fT[(size_t)(s + 2) * 256 + tid];
      a3 += sW[s + 3] * fT[(size_t)(s + 3) * 256 + tid];
    }
    res = ((a0 + a1) + (a2 + a3)) / fmaxf((float)cnt, 1.0f);
  } else {
    float at = 0.0f;
    for (int r = 0; r < 25; ++r) {
      int p = topIdx[bc * 25 + r];
      int y = p / IMG_W, x = p % IMG_W;
      float sy = (y + 0.5f) * 0.0625f - 0.5f; sy = fminf(fmaxf(sy, 0.0f), 27.0f);
      float sx = (x + 0.5f) * 0.0625f - 0.5f; sx = fminf(fmaxf(sx, 0.0f), 27.0f);
      int fy0 = (int)sy, fx0 = (int)sx;
      int fy1 = min(fy0 + 1, 27), fx1 = min(fx0 + 1, 27);
      float wy = sy - (float)fy0, wx = sx - (float)fx0;
      at += (1.0f - wy) * (1.0f - wx) * fT[(size_t)(fy0 * 28 + fx0) * 256 + tid]
          + (1.0f - wy) * wx          * fT[(size_t)(fy0 * 28 + fx1) * 256 + tid]
          + wy          * (1.0f - wx) * fT[(size_t)(fy1 * 28 + fx0) * 256 + tid]
          + wy          * wx          * fT[(size_t)(fy1 * 28 + fx1) * 256 + tid];
    }
    res = at * (1.0f / 25.0f);
  }
  fsm_g[(size_t)bc * 256 + tid] = res;
}

// ---------------------------------------------------------------------------
// K4: sequential loss over b with EMA memory bank. Single block, 256 threads.
__global__ __launch_bounds__(256) void k_loss(const float* __restrict__ fsm_g,
                                              const float* __restrict__ cls_label,
                                              const float* __restrict__ proj_w,
                                              const float* __restrict__ fc_init,
                                              float* __restrict__ out) {
  __shared__ float sFsm[NCLS * LK];
  __shared__ float sFc[NCLS * LK];
  __shared__ float sPw[NCLS * LK];
  __shared__ float sMat[NCLS * NCLS];
  __shared__ float sRow[NCLS];
  __shared__ float sNormI[NCLS], sNormC[NCLS];
  __shared__ int   sQual[NCLS];
  __shared__ float sPres[2][NCLS];
  __shared__ float sScal[2];
  int tid = threadIdx.x;
  for (int r = 0; r < NCLS; ++r) {
    sFc[r * LK + tid] = fc_init[r * 256 + tid];
    sPw[r * LK + tid] = proj_w[r * 256 + tid];
  }
  if (tid < 40) sPres[tid / NCLS][tid % NCLS] = cls_label[tid];
  if (tid == 0) { sScal[0] = 0.0f; sScal[1] = 0.0f; }
  __syncthreads();

  for (int b = 0; b < 2; ++b) {
    for (int r = 0; r < NCLS; ++r) sFsm[r * LK + tid] = fsm_g[(b * NCLS + r) * 256 + tid];
    __syncthreads();
    if (tid < NCLS) {
      float s = 0.0f, t2 = 0.0f;
      for (int d = 0; d < 256; ++d) {
        float a = sFsm[tid * LK + d]; s += a * a;
        float f = sFc[tid * LK + d];  t2 += f * f;
      }
      sNormI[tid] = fmaxf(sqrtf(s), 1e-12f);
      sNormC[tid] = fmaxf(sqrtf(t2), 1e-12f);
    }
    __syncthreads();
    for (int pi = tid; pi < 400; pi += 256) {
      int i = pi / NCLS, j = pi % NCLS;
      float acc = 0.0f;
      for (int d = 0; d < 256; ++d) acc += sFsm[i * LK + d] * sFc[j * LK + d];
      float c0 = fabsf(acc / (sNormI[i] * sNormC[j]));
      sMat[pi] = fminf(fmaxf(c0, 1e-5f), 1.0f - 1e-5f);
    }
    __syncthreads();
    if (tid < NCLS) {
      float pres = (sPres[b][tid] > 0.5f) ? 1.0f : 0.0f;
      float rs = 0.0f, om = -3.0e38f;
      for (int j = 0; j < NCLS; ++j) {
        float c0 = sMat[tid * NCLS + j];
        float ident = (j == tid) ? pres : 0.0f;
        rs += ident * logf(c0) + (1.0f - ident) * log1pf(-c0);
        if (j != tid) om = fmaxf(om, c0);
      }
      sRow[tid] = rs;
      sQual[tid] = (pres > 0.5f && om < 0.6f) ? 1 : 0;
    }
    __syncthreads();
    if (tid == 0) {
      float s = 0.0f;
      for (int r = 0; r < NCLS; ++r) s += sRow[r];
      sScal[0] -= s / 400.0f;
    }
    __syncthreads();
    for (int pi = tid; pi < 400; pi += 256) {
      int i = pi / NCLS, j = pi % NCLS;
      float acc = 0.0f;
      for (int d = 0; d < 256; ++d) acc += sFsm[i * LK + d] * sPw[j * LK + d];
      sMat[pi] = acc;
    }
    __syncthreads();
    if (tid < NCLS) {
      float m = -3.0e38f;
      for (int j = 0; j < NCLS; ++j) m = fmaxf(m, sMat[tid * NCLS + j]);
      float S = 0.0f;
      for (int j = 0; j < NCLS; ++j) S += expf(sMat[tid * NCLS + j] - m);
      float ts = 0.0f;
      for (int j = 0; j < NCLS; ++j) {
        float p = expf(sMat[tid * NCLS + j] - m) / S;
        if (j == tid) ts += fmaxf(logf(p), -100.0f);
        else          ts += fmaxf(log1pf(-p), -100.0f);
      }
      sRow[tid] = -ts / 20.0f;
    }
    __syncthreads();
    if (tid == 0) {
      float add = 0.0f; int n = 0;
      for (int r = 0; r < NCLS; ++r) if (sQual[r]) { add += sRow[r]; n++; }
      float lc = sScal[1] + add;
      if (n > 0) lc = lc / fmaxf((float)n, 1.0f);
      sScal[1] = lc;
    }
    __syncthreads();
    for (int r = 0; r < NCLS; ++r)
      if (sQual[r]) sFc[r * LK + tid] = 0.95f * sFc[r * LK + tid] + 0.05f * sFsm[r * LK + tid];
    __syncthreads();
  }
  if (tid == 0) out[0] = sScal[0] + sScal[1];
}

// ---------------------------------------------------------------------------
extern "C" void kernel_launch(void* const* d_in, const int* in_sizes, int n_in,
                              void* d_out, int out_size, void* d_ws, size_t ws_size,
                              hipStream_t stream) {
  const float* fmap      = (const float*)d_in[0];
  const float* cam       = (const float*)d_in[1];
  const float* cls_label = (const float*)d_in[2];
  const float* proj_w    = (const float*)d_in[3];
  const float* fc_init   = (const float*)d_in[4];
  const float* hig       = (const float*)d_in[5];
  const float* low       = (const float*)d_in[6];
  const float* bg        = (const float*)d_in[7];
  float* out = (float*)d_out;

  char* ws = (char*)d_ws;
  float* W       = (float*)(ws);                 // 31360 floats (125440 B)
  int*   counts  = (int*)  (ws + 125440);        // 40 ints
  int*   candCnt = (int*)  (ws + 125600);        // 40 ints
  int*   topIdx  = (int*)  (ws + 125760);        // 1000 ints (4000 B)
  float* fsm     = (float*)(ws + 129760);        // 10240 floats (40960 B)
  float* candV   = (float*)(ws + 170720);        // 40*2560 floats (409600 B)
  int*   candI   = (int*)  (ws + 580320);        // 40*2560 ints   (409600 B)
  float* fmapT   = (float*)(ws + 989920);        // 401408 floats  (1605632 B)

  hipMemsetAsync(ws, 0, 125760, stream);         // zero W + counts + candCnt
  k_transpose    <<< 400, 256, 0, stream>>>(fmap, fmapT);
  k_pseudo_filter<<< 392, 256, 0, stream>>>(cam, cls_label, hig, low, bg,
                                            W, counts, candCnt, candV, candI);
  k_select       <<<  40, 256, 0, stream>>>(cam, cls_label, counts, candCnt, candV, candI, topIdx);
  k_features     <<<  40, 256, 0, stream>>>(fmapT, W, counts, topIdx, cls_label, fsm);
  k_loss         <<<   1, 256, 0, stream>>>(fsm, cls_label, proj_w, fc_init, out);
}

// Round 4
// 292.102 us; speedup vs baseline: 1.4106x; 1.4106x over previous
//
#include <hip/hip_runtime.h>
#include <cstdint>

#define HW 200704      // 448*448
#define IMG_W 448
#define NCLS 20
#define NDIM 256
#define CAPG 2560      // candidate cap per (b,c); mean 2007, sd 45 at T=0.99
#define TFILT 0.99f
#define LK 257         // padded LDS stride (257 mod 32 == 1 -> conflict-free)

// ---------------------------------------------------------------------------
// K0: coalesced transpose fmap [B,256,784] -> fmapT [B,784,256] via LDS tiles.
__global__ __launch_bounds__(256) void k_transpose(const float* __restrict__ fmap,
                                                   float* __restrict__ fmapT) {
  __shared__ float tile[32][33];
  int blk = blockIdx.x;
  int b = blk / 200;
  int t = blk % 200;
  int dT = t / 25, sT = t % 25;
  int ty = threadIdx.x >> 5;
  int tx = threadIdx.x & 31;
#pragma unroll
  for (int r = 0; r < 4; ++r) {
    int d = dT * 32 + ty + r * 8;
    int s = sT * 32 + tx;
    if (s < 784) tile[ty + r * 8][tx] = fmap[((size_t)(b * 256 + d)) * 784 + s];
  }
  __syncthreads();
#pragma unroll
  for (int r = 0; r < 4; ++r) {
    int s = sT * 32 + ty + r * 8;
    int d = dT * 32 + tx;
    if (s < 784) fmapT[((size_t)(b * 784 + s)) * 256 + d] = tile[tx][ty + r * 8];
  }
}

// ---------------------------------------------------------------------------
// K1: fused pseudo-label + weight scatter + candidate filter.
// PHASE-SEPARATED: 20 back-to-back float2 loads -> branchless consume ->
// rare atomic appends. grid = 2*392 blocks, 2 pixels/thread.
__global__ __launch_bounds__(256) void k_pseudo_filter(const float* __restrict__ cam,
                                                       const float* __restrict__ cls_label,
                                                       const float* __restrict__ hig_p,
                                                       const float* __restrict__ low_p,
                                                       const float* __restrict__ bg_p,
                                                       float* __restrict__ W,
                                                       int* __restrict__ counts,
                                                       int* __restrict__ candCnt,
                                                       int* __restrict__ candI) {
  int b = blockIdx.x / 392;
  int pix0 = (blockIdx.x % 392) * 512 + threadIdx.x * 2;
  __shared__ float sLab[NCLS];
  if (threadIdx.x < NCLS) sLab[threadIdx.x] = cls_label[b * NCLS + threadIdx.x];
  __syncthreads();
  const float* base = cam + (size_t)b * NCLS * HW + pix0;

  // ---- phase 1: issue all 20 loads, nothing in between ----
  float2 v[NCLS];
#pragma unroll
  for (int c = 0; c < NCLS; ++c) v[c] = *(const float2*)(base + (size_t)c * HW);

  // ---- phase 2: branchless consume ----
  float top1[2] = {-1.0f, -1.0f}, sec[2] = {-1.0f, -1.0f};
  int idx1[2] = {0, 0};
  unsigned cm[2] = {0u, 0u};
#pragma unroll
  for (int c = 0; c < NCLS; ++c) {
    float lab = sLab[c];
    float vv[2] = {v[c].x * lab, v[c].y * lab};
#pragma unroll
    for (int u = 0; u < 2; ++u) {
      float x = vv[u];
      // ascending c + strict '>' == lowest-index tie-break (JAX top_k)
      bool gt = x > top1[u];
      sec[u] = gt ? top1[u] : fmaxf(sec[u], fminf(x, top1[u]));
      idx1[u] = gt ? c : idx1[u];
      top1[u] = gt ? x : top1[u];
      cm[u] |= (x >= TFILT) ? (1u << c) : 0u;
    }
  }

  // ---- phase 3: rare side effects ----
  float hig = hig_p[0], low = low_p[0], bg = bg_p[0];
#pragma unroll
  for (int u = 0; u < 2; ++u) {
    unsigned m = cm[u];
    while (m) {
      int c = __builtin_ctz(m); m &= m - 1u;
      int pos = atomicAdd(&candCnt[b * NCLS + c], 1);
      if (pos < CAPG) candI[(size_t)(b * NCLS + c) * CAPG + pos] = pix0 + u;
    }
    int ps = idx1[u] + 1;
    float t1 = top1[u];
    if (t1 < hig) ps = 255;
    if (t1 < low) ps = 0;
    if (t1 < bg)  ps = 0;
    if ((t1 - sec[u] < 0.3f) && (t1 > hig)) ps = 255;
    if (ps >= 1 && ps <= NCLS) {
      int cls = ps - 1;
      int pix = pix0 + u;
      int y = pix / IMG_W, x = pix % IMG_W;
      float sy = (y + 0.5f) * 0.0625f - 0.5f; sy = fminf(fmaxf(sy, 0.0f), 27.0f);
      float sx = (x + 0.5f) * 0.0625f - 0.5f; sx = fminf(fmaxf(sx, 0.0f), 27.0f);
      int fy0 = (int)sy, fx0 = (int)sx;
      int fy1 = min(fy0 + 1, 27), fx1 = min(fx0 + 1, 27);
      float wy = sy - (float)fy0, wx = sx - (float)fx0;
      float* Wb = W + (size_t)(b * NCLS + cls) * 784;
      atomicAdd(&Wb[fy0 * 28 + fx0], (1.0f - wy) * (1.0f - wx));
      atomicAdd(&Wb[fy0 * 28 + fx1], (1.0f - wy) * wx);
      atomicAdd(&Wb[fy1 * 28 + fx0], wy * (1.0f - wx));
      atomicAdd(&Wb[fy1 * 28 + fx1], wy * wx);
      atomicAdd(&counts[b * NCLS + cls], 1);
    }
  }
}

// ---------------------------------------------------------------------------
// K2: merged select+features. 40 blocks x 1024 threads (16 waves for latency
// hiding; 1 block/CU). cnt>0 -> split-K W-dot; cnt==0 -> exact top-25
// tournament (JAX tie-break) + 25 bilinear gathers.
__global__ __launch_bounds__(1024) void k_features(const float* __restrict__ fmapT,
                                                   const float* __restrict__ cam,
                                                   const float* __restrict__ W,
                                                   const int* __restrict__ counts,
                                                   const int* __restrict__ candCnt,
                                                   const int* __restrict__ candI,
                                                   const float* __restrict__ cls_label,
                                                   float* __restrict__ fsm_g) {
  __shared__ float sW[784];
  __shared__ float sPart[4][256];
  __shared__ float cv[CAPG]; __shared__ int ci[CAPG];
  __shared__ float wv[16]; __shared__ int wi[16];
  __shared__ float selV; __shared__ int selI;
  __shared__ int sTop[25];
  int bc = blockIdx.x;
  int b = bc / NCLS;
  int tid = threadIdx.x;
  int dim = tid & 255, part = tid >> 8;   // 4-way K split
  if (cls_label[bc] == 0.0f) {
    if (tid < 256) fsm_g[(size_t)bc * 256 + tid] = 0.0f;
    return;
  }
  int cnt = counts[bc];
  const float* fT = fmapT + (size_t)b * 784 * 256;
  float res = 0.0f;
  if (cnt > 0) {
    for (int s = tid; s < 784; s += 1024) sW[s] = W[(size_t)bc * 784 + s];
    __syncthreads();
    float a0 = 0.0f, a1 = 0.0f, a2 = 0.0f, a3 = 0.0f;
    int s0 = part * 196;
    for (int s = s0; s < s0 + 196; s += 4) {
      a0 += sW[s]     * fT[(size_t)(s)     * 256 + dim];
      a1 += sW[s + 1] * fT[(size_t)(s + 1) * 256 + dim];
      a2 += sW[s + 2] * fT[(size_t)(s + 2) * 256 + dim];
      a3 += sW[s + 3] * fT[(size_t)(s + 3) * 256 + dim];
    }
    sPart[part][dim] = (a0 + a1) + (a2 + a3);
    __syncthreads();
    if (tid < 256)
      res = ((sPart[0][tid] + sPart[1][tid]) + (sPart[2][tid] + sPart[3][tid]))
            / fmaxf((float)cnt, 1.0f);
  } else {
    int n = candCnt[bc];
    bool fb = (n < 25) || (n > CAPG);      // exact fallback (never in practice)
    const float* camc = cam + (size_t)bc * HW;   // lab==1 -> valid_cam == cam
    if (!fb) {
      for (int p = tid; p < n; p += 1024) {
        int ix = candI[(size_t)bc * CAPG + p];
        ci[p] = ix; cv[p] = camc[ix];
      }
    }
    __syncthreads();
    float lastV = 3.0e38f; int lastI = -1;
    for (int r = 0; r < 25; ++r) {
      float bv = -1.0e30f; int bi = 0x7fffffff;
      if (!fb) {
        for (int p = tid; p < n; p += 1024) {
          float vv = cv[p]; int ii = ci[p];
          if (((vv < lastV) || (vv == lastV && ii > lastI)) &&
              ((vv > bv) || (vv == bv && ii < bi))) { bv = vv; bi = ii; }
        }
      } else {
        for (int p = tid; p < HW; p += 1024) {
          float vv = camc[p];
          if (((vv < lastV) || (vv == lastV && p > lastI)) &&
              ((vv > bv) || (vv == bv && p < bi))) { bv = vv; bi = p; }
        }
      }
      for (int off = 32; off > 0; off >>= 1) {
        float ov = __shfl_xor(bv, off, 64);
        int   oi = __shfl_xor(bi, off, 64);
        if (ov > bv || (ov == bv && oi < bi)) { bv = ov; bi = oi; }
      }
      if ((tid & 63) == 0) { wv[tid >> 6] = bv; wi[tid >> 6] = bi; }
      __syncthreads();
      if (tid == 0) {
        for (int w = 1; w < 16; ++w)
          if (wv[w] > bv || (wv[w] == bv && wi[w] < bi)) { bv = wv[w]; bi = wi[w]; }
        selV = bv; selI = bi; sTop[r] = bi;
      }
      __syncthreads();
      lastV = selV; lastI = selI;
    }
    float at = 0.0f;
    for (int r = part; r < 25; r += 4) {
      int p = sTop[r];
      int y = p / IMG_W, x = p % IMG_W;
      float sy = (y + 0.5f) * 0.0625f - 0.5f; sy = fminf(fmaxf(sy, 0.0f), 27.0f);
      float sx = (x + 0.5f) * 0.0625f - 0.5f; sx = fminf(fmaxf(sx, 0.0f), 27.0f);
      int fy0 = (int)sy, fx0 = (int)sx;
      int fy1 = min(fy0 + 1, 27), fx1 = min(fx0 + 1, 27);
      float wy = sy - (float)fy0, wx = sx - (float)fx0;
      at += (1.0f - wy) * (1.0f - wx) * fT[(size_t)(fy0 * 28 + fx0) * 256 + dim]
          + (1.0f - wy) * wx          * fT[(size_t)(fy0 * 28 + fx1) * 256 + dim]
          + wy          * (1.0f - wx) * fT[(size_t)(fy1 * 28 + fx0) * 256 + dim]
          + wy          * wx          * fT[(size_t)(fy1 * 28 + fx1) * 256 + dim];
    }
    sPart[part][dim] = at;
    __syncthreads();
    if (tid < 256)
      res = ((sPart[0][tid] + sPart[1][tid]) + (sPart[2][tid] + sPart[3][tid])) * (1.0f / 25.0f);
  }
  if (tid < 256) fsm_g[(size_t)bc * 256 + tid] = res;
}

// ---------------------------------------------------------------------------
// K4: sequential loss over b with EMA memory bank. Single block, 256 threads.
__global__ __launch_bounds__(256) void k_loss(const float* __restrict__ fsm_g,
                                              const float* __restrict__ cls_label,
                                              const float* __restrict__ proj_w,
                                              const float* __restrict__ fc_init,
                                              float* __restrict__ out) {
  __shared__ float sFsm[NCLS * LK];
  __shared__ float sFc[NCLS * LK];
  __shared__ float sPw[NCLS * LK];
  __shared__ float sMat[NCLS * NCLS];
  __shared__ float sRow[NCLS];
  __shared__ float sNormI[NCLS], sNormC[NCLS];
  __shared__ int   sQual[NCLS];
  __shared__ float sPres[2][NCLS];
  __shared__ float sScal[2];
  int tid = threadIdx.x;
  for (int r = 0; r < NCLS; ++r) {
    sFc[r * LK + tid] = fc_init[r * 256 + tid];
    sPw[r * LK + tid] = proj_w[r * 256 + tid];
  }
  if (tid < 40) sPres[tid / NCLS][tid % NCLS] = cls_label[tid];
  if (tid == 0) { sScal[0] = 0.0f; sScal[1] = 0.0f; }
  __syncthreads();

  for (int b = 0; b < 2; ++b) {
    for (int r = 0; r < NCLS; ++r) sFsm[r * LK + tid] = fsm_g[(b * NCLS + r) * 256 + tid];
    __syncthreads();
    if (tid < NCLS) {
      float s = 0.0f, t2 = 0.0f;
      for (int d = 0; d < 256; ++d) {
        float a = sFsm[tid * LK + d]; s += a * a;
        float f = sFc[tid * LK + d];  t2 += f * f;
      }
      sNormI[tid] = fmaxf(sqrtf(s), 1e-12f);
      sNormC[tid] = fmaxf(sqrtf(t2), 1e-12f);
    }
    __syncthreads();
    for (int pi = tid; pi < 400; pi += 256) {
      int i = pi / NCLS, j = pi % NCLS;
      float acc = 0.0f;
      for (int d = 0; d < 256; ++d) acc += sFsm[i * LK + d] * sFc[j * LK + d];
      float c0 = fabsf(acc / (sNormI[i] * sNormC[j]));
      sMat[pi] = fminf(fmaxf(c0, 1e-5f), 1.0f - 1e-5f);
    }
    __syncthreads();
    if (tid < NCLS) {
      float pres = (sPres[b][tid] > 0.5f) ? 1.0f : 0.0f;
      float rs = 0.0f, om = -3.0e38f;
      for (int j = 0; j < NCLS; ++j) {
        float c0 = sMat[tid * NCLS + j];
        float ident = (j == tid) ? pres : 0.0f;
        rs += ident * logf(c0) + (1.0f - ident) * log1pf(-c0);
        if (j != tid) om = fmaxf(om, c0);
      }
      sRow[tid] = rs;
      sQual[tid] = (pres > 0.5f && om < 0.6f) ? 1 : 0;
    }
    __syncthreads();
    if (tid == 0) {
      float s = 0.0f;
      for (int r = 0; r < NCLS; ++r) s += sRow[r];
      sScal[0] -= s / 400.0f;
    }
    __syncthreads();
    for (int pi = tid; pi < 400; pi += 256) {
      int i = pi / NCLS, j = pi % NCLS;
      float acc = 0.0f;
      for (int d = 0; d < 256; ++d) acc += sFsm[i * LK + d] * sPw[j * LK + d];
      sMat[pi] = acc;
    }
    __syncthreads();
    if (tid < NCLS) {
      float m = -3.0e38f;
      for (int j = 0; j < NCLS; ++j) m = fmaxf(m, sMat[tid * NCLS + j]);
      float S = 0.0f;
      for (int j = 0; j < NCLS; ++j) S += expf(sMat[tid * NCLS + j] - m);
      float ts = 0.0f;
      for (int j = 0; j < NCLS; ++j) {
        float p = expf(sMat[tid * NCLS + j] - m) / S;
        if (j == tid) ts += fmaxf(logf(p), -100.0f);
        else          ts += fmaxf(log1pf(-p), -100.0f);
      }
      sRow[tid] = -ts / 20.0f;
    }
    __syncthreads();
    if (tid == 0) {
      float add = 0.0f; int n = 0;
      for (int r = 0; r < NCLS; ++r) if (sQual[r]) { add += sRow[r]; n++; }
      float lc = sScal[1] + add;
      if (n > 0) lc = lc / fmaxf((float)n, 1.0f);
      sScal[1] = lc;
    }
    __syncthreads();
    for (int r = 0; r < NCLS; ++r)
      if (sQual[r]) sFc[r * LK + tid] = 0.95f * sFc[r * LK + tid] + 0.05f * sFsm[r * LK + tid];
    __syncthreads();
  }
  if (tid == 0) out[0] = sScal[0] + sScal[1];
}

// ---------------------------------------------------------------------------
extern "C" void kernel_launch(void* const* d_in, const int* in_sizes, int n_in,
                              void* d_out, int out_size, void* d_ws, size_t ws_size,
                              hipStream_t stream) {
  const float* fmap      = (const float*)d_in[0];
  const float* cam       = (const float*)d_in[1];
  const float* cls_label = (const float*)d_in[2];
  const float* proj_w    = (const float*)d_in[3];
  const float* fc_init   = (const float*)d_in[4];
  const float* hig       = (const float*)d_in[5];
  const float* low       = (const float*)d_in[6];
  const float* bg        = (const float*)d_in[7];
  float* out = (float*)d_out;

  char* ws = (char*)d_ws;
  float* W       = (float*)(ws);                 // 31360 floats (125440 B)
  int*   counts  = (int*)  (ws + 125440);        // 40 ints
  int*   candCnt = (int*)  (ws + 125600);        // 40 ints
  float* fsm     = (float*)(ws + 125760);        // 10240 floats (40960 B)
  int*   candI   = (int*)  (ws + 166720);        // 40*2560 ints (409600 B)
  float* fmapT   = (float*)(ws + 576320);        // 401408 floats (1605632 B)

  hipMemsetAsync(ws, 0, 125760, stream);         // zero W + counts + candCnt
  k_transpose    <<< 400,  256, 0, stream>>>(fmap, fmapT);
  k_pseudo_filter<<< 784,  256, 0, stream>>>(cam, cls_label, hig, low, bg,
                                             W, counts, candCnt, candI);
  k_features     <<<  40, 1024, 0, stream>>>(fmapT, cam, W, counts, candCnt, candI, cls_label, fsm);
  k_loss         <<<   1,  256, 0, stream>>>(fsm, cls_label, proj_w, fc_init, out);
}

// Round 5
// 232.507 us; speedup vs baseline: 1.7722x; 1.2563x over previous
//
#include <hip/hip_runtime.h>
#include <cstdint>

#define HW 200704      // 448*448
#define IMG_W 448
#define NCLS 20
#define NDIM 256
#define NBLK 392       // cam blocks per batch (512 px each)
#define CAPB 12        // per-(class,block) candidate slots; mean 5.12
#define CAPG 2560      // global candidate cap per (b,c); mean 2016, sd 45
#define TFILT 0.99f
#define LK 257         // padded LDS stride (257 mod 32 == 1 -> conflict-free)

// ---------------------------------------------------------------------------
// K1: fused pseudo-label + bilinear weight scatter + candidate filter.
// NO global return-atomics: candidates go to fixed per-(class,block) slots
// reserved via LDS atomics; W/counts use fire-and-forget global atomics.
__global__ __launch_bounds__(256) void k_pseudo_filter(const float* __restrict__ cam,
                                                       const float* __restrict__ cls_label,
                                                       const float* __restrict__ hig_p,
                                                       const float* __restrict__ low_p,
                                                       const float* __restrict__ bg_p,
                                                       float* __restrict__ W,
                                                       int* __restrict__ counts,
                                                       int* __restrict__ cntBlk,
                                                       int* __restrict__ candIdx) {
  int b = blockIdx.x / NBLK;
  int blkInB = blockIdx.x % NBLK;
  int pix0 = blkInB * 512 + threadIdx.x * 2;
  __shared__ float sLab[NCLS];
  __shared__ int sCnt[NCLS];
  if (threadIdx.x < NCLS) {
    sLab[threadIdx.x] = cls_label[b * NCLS + threadIdx.x];
    sCnt[threadIdx.x] = 0;
  }
  __syncthreads();
  const float* base = cam + (size_t)b * NCLS * HW + pix0;

  // ---- phase 1: issue all 20 loads, nothing in between ----
  float2 v[NCLS];
#pragma unroll
  for (int c = 0; c < NCLS; ++c) v[c] = *(const float2*)(base + (size_t)c * HW);

  // ---- phase 2: branchless consume ----
  float top1[2] = {-1.0f, -1.0f}, sec[2] = {-1.0f, -1.0f};
  int idx1[2] = {0, 0};
  unsigned cm[2] = {0u, 0u};
#pragma unroll
  for (int c = 0; c < NCLS; ++c) {
    float lab = sLab[c];
    float vv[2] = {v[c].x * lab, v[c].y * lab};
#pragma unroll
    for (int u = 0; u < 2; ++u) {
      float x = vv[u];
      // ascending c + strict '>' == lowest-index tie-break (JAX top_k)
      bool gt = x > top1[u];
      sec[u] = gt ? top1[u] : fmaxf(sec[u], fminf(x, top1[u]));
      idx1[u] = gt ? c : idx1[u];
      top1[u] = gt ? x : top1[u];
      cm[u] |= (x >= TFILT) ? (1u << c) : 0u;
    }
  }

  // ---- phase 3: rare side effects (LDS-atomic slot reserve; no return-atomics) ----
  float hig = hig_p[0], low = low_p[0], bg = bg_p[0];
#pragma unroll
  for (int u = 0; u < 2; ++u) {
    unsigned m = cm[u];
    while (m) {
      int c = __builtin_ctz(m); m &= m - 1u;
      int pos = atomicAdd(&sCnt[c], 1);          // LDS atomic: fast, block-local
      if (pos < CAPB)
        candIdx[(size_t)((b * NCLS + c) * NBLK + blkInB) * CAPB + pos] = pix0 + u;
    }
    int ps = idx1[u] + 1;
    float t1 = top1[u];
    if (t1 < hig) ps = 255;
    if (t1 < low) ps = 0;
    if (t1 < bg)  ps = 0;
    if ((t1 - sec[u] < 0.3f) && (t1 > hig)) ps = 255;
    if (ps >= 1 && ps <= NCLS) {
      int cls = ps - 1;
      int pix = pix0 + u;
      int y = pix / IMG_W, x = pix % IMG_W;
      float sy = (y + 0.5f) * 0.0625f - 0.5f; sy = fminf(fmaxf(sy, 0.0f), 27.0f);
      float sx = (x + 0.5f) * 0.0625f - 0.5f; sx = fminf(fmaxf(sx, 0.0f), 27.0f);
      int fy0 = (int)sy, fx0 = (int)sx;
      int fy1 = min(fy0 + 1, 27), fx1 = min(fx0 + 1, 27);
      float wy = sy - (float)fy0, wx = sx - (float)fx0;
      float* Wb = W + (size_t)(b * NCLS + cls) * 784;
      atomicAdd(&Wb[fy0 * 28 + fx0], (1.0f - wy) * (1.0f - wx));   // no return: pipelined
      atomicAdd(&Wb[fy0 * 28 + fx1], (1.0f - wy) * wx);
      atomicAdd(&Wb[fy1 * 28 + fx0], wy * (1.0f - wx));
      atomicAdd(&Wb[fy1 * 28 + fx1], wy * wx);
      atomicAdd(&counts[b * NCLS + cls], 1);
    }
  }
  __syncthreads();
  if (threadIdx.x < NCLS)
    cntBlk[(b * NCLS + threadIdx.x) * NBLK + blkInB] = sCnt[threadIdx.x];
}

// ---------------------------------------------------------------------------
// K2: fused features + loss. 40 blocks x 1024 threads. Reads fmap directly
// (per-thread contiguous float4 rows -> no transpose kernel). Last block
// (device-scope ticket) runs the sequential loss.
__global__ __launch_bounds__(1024) void k_features_loss(const float* __restrict__ fmap,
                                                        const float* __restrict__ cam,
                                                        const float* __restrict__ Wg,
                                                        const int* __restrict__ counts,
                                                        const int* __restrict__ cntBlk,
                                                        const int* __restrict__ candIdx,
                                                        const float* __restrict__ cls_label,
                                                        const float* __restrict__ proj_w,
                                                        const float* __restrict__ fc_init,
                                                        int* __restrict__ done,
                                                        float* __restrict__ fsm_g,
                                                        float* __restrict__ out) {
  __shared__ float sW[784];
  __shared__ float sPart[4][256];
  __shared__ float cv[CAPG]; __shared__ int ci[CAPG];
  __shared__ float wv[16]; __shared__ int wi[16];
  __shared__ float selV; __shared__ int selI;
  __shared__ int sTop[25];
  __shared__ int sN, sFb, sLast;
  // loss state
  __shared__ float sFsm[NCLS * LK], sFc[NCLS * LK], sPw[NCLS * LK];
  __shared__ float sMat[NCLS * NCLS], sRow[NCLS], sNormI[NCLS], sNormC[NCLS];
  __shared__ int   sQual[NCLS];
  __shared__ float sPres[2][NCLS];
  __shared__ float sScal[2];

  int bc = blockIdx.x;
  int b = bc / NCLS;
  int tid = threadIdx.x;
  int dim = tid & 255, part = tid >> 8;   // 4-way K split
  bool present = (cls_label[bc] != 0.0f);
  int cnt = counts[bc];
  float res = 0.0f;

  if (present) {
    if (cnt > 0) {
      for (int s = tid; s < 784; s += 1024) sW[s] = Wg[(size_t)bc * 784 + s];
      __syncthreads();
      const float* row = fmap + ((size_t)(b * 256 + dim)) * 784 + part * 196;
      const float* wp = sW + part * 196;
      float a0 = 0.0f, a1 = 0.0f, a2 = 0.0f, a3 = 0.0f;
      for (int s = 0; s < 196; s += 4) {
        float4 f = *(const float4*)(row + s);
        a0 += wp[s]     * f.x;
        a1 += wp[s + 1] * f.y;
        a2 += wp[s + 2] * f.z;
        a3 += wp[s + 3] * f.w;
      }
      sPart[part][dim] = (a0 + a1) + (a2 + a3);
      __syncthreads();
      if (tid < 256)
        res = ((sPart[0][tid] + sPart[1][tid]) + (sPart[2][tid] + sPart[3][tid]))
              / fmaxf((float)cnt, 1.0f);
    } else {
      // ---- exact top-25 (JAX tie-break) from per-block candidate lists ----
      if (tid == 0) { sN = 0; sFb = 0; }
      __syncthreads();
      const float* camc = cam + (size_t)bc * HW;   // lab==1 -> valid_cam == cam
      if (tid < NBLK) {
        int cb = cntBlk[(size_t)bc * NBLK + tid];
        if (cb > CAPB) sFb = 1;                    // overflow -> exact full scan
        else if (cb > 0) {
          int base = atomicAdd(&sN, cb);
          for (int j = 0; j < cb; ++j) {
            int p = base + j;
            if (p < CAPG) ci[p] = candIdx[(size_t)((size_t)bc * NBLK + tid) * CAPB + j];
          }
        }
      }
      __syncthreads();
      int n = sN;
      bool fb = sFb || (n < 25) || (n > CAPG);
      if (!fb) for (int p = tid; p < n; p += 1024) cv[p] = camc[ci[p]];
      __syncthreads();
      float lastV = 3.0e38f; int lastI = -1;
      for (int r = 0; r < 25; ++r) {
        float bv = -1.0e30f; int bi = 0x7fffffff;
        if (!fb) {
          for (int p = tid; p < n; p += 1024) {
            float vv = cv[p]; int ii = ci[p];
            if (((vv < lastV) || (vv == lastV && ii > lastI)) &&
                ((vv > bv) || (vv == bv && ii < bi))) { bv = vv; bi = ii; }
          }
        } else {
          for (int p = tid; p < HW; p += 1024) {
            float vv = camc[p];
            if (((vv < lastV) || (vv == lastV && p > lastI)) &&
                ((vv > bv) || (vv == bv && p < bi))) { bv = vv; bi = p; }
          }
        }
        for (int off = 32; off > 0; off >>= 1) {
          float ov = __shfl_xor(bv, off, 64);
          int   oi = __shfl_xor(bi, off, 64);
          if (ov > bv || (ov == bv && oi < bi)) { bv = ov; bi = oi; }
        }
        if ((tid & 63) == 0) { wv[tid >> 6] = bv; wi[tid >> 6] = bi; }
        __syncthreads();
        if (tid == 0) {
          for (int w = 1; w < 16; ++w)
            if (wv[w] > bv || (wv[w] == bv && wi[w] < bi)) { bv = wv[w]; bi = wi[w]; }
          selV = bv; selI = bi; sTop[r] = bi;
        }
        __syncthreads();
        lastV = selV; lastI = selI;
      }
      float at = 0.0f;
      for (int r = part; r < 25; r += 4) {
        int p = sTop[r];
        int y = p / IMG_W, x = p % IMG_W;
        float sy = (y + 0.5f) * 0.0625f - 0.5f; sy = fminf(fmaxf(sy, 0.0f), 27.0f);
        float sx = (x + 0.5f) * 0.0625f - 0.5f; sx = fminf(fmaxf(sx, 0.0f), 27.0f);
        int fy0 = (int)sy, fx0 = (int)sx;
        int fy1 = min(fy0 + 1, 27), fx1 = min(fx0 + 1, 27);
        float wy = sy - (float)fy0, wx = sx - (float)fx0;
        const float* fb0 = fmap + ((size_t)(b * 256 + dim)) * 784;
        at += (1.0f - wy) * (1.0f - wx) * fb0[fy0 * 28 + fx0]
            + (1.0f - wy) * wx          * fb0[fy0 * 28 + fx1]
            + wy          * (1.0f - wx) * fb0[fy1 * 28 + fx0]
            + wy          * wx          * fb0[fy1 * 28 + fx1];
      }
      sPart[part][dim] = at;
      __syncthreads();
      if (tid < 256)
        res = ((sPart[0][tid] + sPart[1][tid]) + (sPart[2][tid] + sPart[3][tid])) * (1.0f / 25.0f);
    }
  }
  if (tid < 256) fsm_g[(size_t)bc * 256 + tid] = res;
  __syncthreads();
  // ---- last-block ticket: device-scope release/acquire ----
  if (tid == 0) {
    __threadfence();
    int t = atomicAdd(done, 1);
    sLast = (t == 39) ? 1 : 0;
  }
  __syncthreads();
  if (!sLast) return;
  __threadfence();   // acquire: invalidate before reading other blocks' fsm

  // ================= sequential loss (identical math to prior rounds) ======
  if (tid < 256) {
    for (int r = 0; r < NCLS; ++r) {
      sFc[r * LK + tid] = fc_init[r * 256 + tid];
      sPw[r * LK + tid] = proj_w[r * 256 + tid];
    }
  }
  if (tid < 40) sPres[tid / NCLS][tid % NCLS] = cls_label[tid];
  if (tid == 0) { sScal[0] = 0.0f; sScal[1] = 0.0f; }
  __syncthreads();

  for (int bb = 0; bb < 2; ++bb) {
    if (tid < 256)
      for (int r = 0; r < NCLS; ++r) sFsm[r * LK + tid] = fsm_g[(bb * NCLS + r) * 256 + tid];
    __syncthreads();
    if (tid < NCLS) {
      float s = 0.0f, t2 = 0.0f;
      for (int d = 0; d < 256; ++d) {
        float a = sFsm[tid * LK + d]; s += a * a;
        float f = sFc[tid * LK + d];  t2 += f * f;
      }
      sNormI[tid] = fmaxf(sqrtf(s), 1e-12f);
      sNormC[tid] = fmaxf(sqrtf(t2), 1e-12f);
    }
    __syncthreads();
    if (tid < 256) {
      for (int pi = tid; pi < 400; pi += 256) {
        int i = pi / NCLS, j = pi % NCLS;
        float acc = 0.0f;
        for (int d = 0; d < 256; ++d) acc += sFsm[i * LK + d] * sFc[j * LK + d];
        float c0 = fabsf(acc / (sNormI[i] * sNormC[j]));
        sMat[pi] = fminf(fmaxf(c0, 1e-5f), 1.0f - 1e-5f);
      }
    }
    __syncthreads();
    if (tid < NCLS) {
      float pres = (sPres[bb][tid] > 0.5f) ? 1.0f : 0.0f;
      float rs = 0.0f, om = -3.0e38f;
      for (int j = 0; j < NCLS; ++j) {
        float c0 = sMat[tid * NCLS + j];
        float ident = (j == tid) ? pres : 0.0f;
        rs += ident * logf(c0) + (1.0f - ident) * log1pf(-c0);
        if (j != tid) om = fmaxf(om, c0);
      }
      sRow[tid] = rs;
      sQual[tid] = (pres > 0.5f && om < 0.6f) ? 1 : 0;
    }
    __syncthreads();
    if (tid == 0) {
      float s = 0.0f;
      for (int r = 0; r < NCLS; ++r) s += sRow[r];
      sScal[0] -= s / 400.0f;
    }
    __syncthreads();
    if (tid < 256) {
      for (int pi = tid; pi < 400; pi += 256) {
        int i = pi / NCLS, j = pi % NCLS;
        float acc = 0.0f;
        for (int d = 0; d < 256; ++d) acc += sFsm[i * LK + d] * sPw[j * LK + d];
        sMat[pi] = acc;
      }
    }
    __syncthreads();
    if (tid < NCLS) {
      float m = -3.0e38f;
      for (int j = 0; j < NCLS; ++j) m = fmaxf(m, sMat[tid * NCLS + j]);
      float S = 0.0f;
      for (int j = 0; j < NCLS; ++j) S += expf(sMat[tid * NCLS + j] - m);
      float ts = 0.0f;
      for (int j = 0; j < NCLS; ++j) {
        float p = expf(sMat[tid * NCLS + j] - m) / S;
        if (j == tid) ts += fmaxf(logf(p), -100.0f);
        else          ts += fmaxf(log1pf(-p), -100.0f);
      }
      sRow[tid] = -ts / 20.0f;
    }
    __syncthreads();
    if (tid == 0) {
      float add = 0.0f; int nq = 0;
      for (int r = 0; r < NCLS; ++r) if (sQual[r]) { add += sRow[r]; nq++; }
      float lc = sScal[1] + add;
      if (nq > 0) lc = lc / fmaxf((float)nq, 1.0f);
      sScal[1] = lc;
    }
    __syncthreads();
    if (tid < 256) {
      for (int r = 0; r < NCLS; ++r)
        if (sQual[r]) sFc[r * LK + tid] = 0.95f * sFc[r * LK + tid] + 0.05f * sFsm[r * LK + tid];
    }
    __syncthreads();
  }
  if (tid == 0) out[0] = sScal[0] + sScal[1];
}

// ---------------------------------------------------------------------------
extern "C" void kernel_launch(void* const* d_in, const int* in_sizes, int n_in,
                              void* d_out, int out_size, void* d_ws, size_t ws_size,
                              hipStream_t stream) {
  const float* fmap      = (const float*)d_in[0];
  const float* cam       = (const float*)d_in[1];
  const float* cls_label = (const float*)d_in[2];
  const float* proj_w    = (const float*)d_in[3];
  const float* fc_init   = (const float*)d_in[4];
  const float* hig       = (const float*)d_in[5];
  const float* low       = (const float*)d_in[6];
  const float* bg        = (const float*)d_in[7];
  float* out = (float*)d_out;

  char* ws = (char*)d_ws;
  float* W       = (float*)(ws);                 // 40*784 floats   (125440 B)
  int*   counts  = (int*)  (ws + 125440);        // 40 ints         (160 B)
  int*   done    = (int*)  (ws + 125600);        // 1 int (pad 32)
  int*   cntBlk  = (int*)  (ws + 125632);        // 40*392 ints     (62720 B)
  int*   candIdx = (int*)  (ws + 188352);        // 40*392*12 ints  (752640 B)
  float* fsm     = (float*)(ws + 940992);        // 10240 floats    (40960 B)
  // total 981952 B

  hipMemsetAsync(ws, 0, 125632, stream);         // zero W + counts + done
  k_pseudo_filter<<< 2 * NBLK, 256, 0, stream>>>(cam, cls_label, hig, low, bg,
                                                 W, counts, cntBlk, candIdx);
  k_features_loss<<<       40, 1024, 0, stream>>>(fmap, cam, W, counts, cntBlk, candIdx,
                                                  cls_label, proj_w, fc_init, done, fsm, out);
}

// Round 6
// 209.557 us; speedup vs baseline: 1.9663x; 1.1095x over previous
//
#include <hip/hip_runtime.h>
#include <cstdint>

#define HW 200704      // 448*448
#define IMG_W 448
#define NCLS 20
#define NDIM 256
#define NBLK 392       // cam blocks per batch (512 px each)
#define CAPB 12        // per-(class,block) candidate slots; mean 5.12
#define CAPG 2560      // global candidate cap per (b,c); mean 2016
#define TFILT 0.99f
#define LK 258         // padded LDS stride (even for b64; 258%32==2 -> 2-way alias, free)

// ---------------------------------------------------------------------------
// K0: coalesced transpose fmap [B,256,784] -> fmapT [B,784,256] via LDS tiles.
__global__ __launch_bounds__(256) void k_transpose(const float* __restrict__ fmap,
                                                   float* __restrict__ fmapT) {
  __shared__ float tile[32][33];
  int blk = blockIdx.x;
  int b = blk / 200;
  int t = blk % 200;
  int dT = t / 25, sT = t % 25;
  int ty = threadIdx.x >> 5;
  int tx = threadIdx.x & 31;
#pragma unroll
  for (int r = 0; r < 4; ++r) {
    int d = dT * 32 + ty + r * 8;
    int s = sT * 32 + tx;
    if (s < 784) tile[ty + r * 8][tx] = fmap[((size_t)(b * 256 + d)) * 784 + s];
  }
  __syncthreads();
#pragma unroll
  for (int r = 0; r < 4; ++r) {
    int s = sT * 32 + ty + r * 8;
    int d = dT * 32 + tx;
    if (s < 784) fmapT[((size_t)(b * 784 + s)) * 256 + d] = tile[tx][ty + r * 8];
  }
}

// ---------------------------------------------------------------------------
// K1: fused pseudo-label + weight scatter + candidate filter.
// LDS-staged: each wave stages 5 classes (10 independent float4 loads ->
// ds_writes, coalesced 1 KB/wave/instr), then consume from LDS.
__global__ __launch_bounds__(256) void k_pseudo_filter(const float* __restrict__ cam,
                                                       const float* __restrict__ cls_label,
                                                       const float* __restrict__ hig_p,
                                                       const float* __restrict__ low_p,
                                                       const float* __restrict__ bg_p,
                                                       float* __restrict__ W,
                                                       int* __restrict__ counts,
                                                       int* __restrict__ cntBlk,
                                                       int* __restrict__ candIdx) {
  __shared__ float sT[NCLS][512];      // 40 KB tile
  __shared__ float sLab[NCLS];
  __shared__ int sCnt[NCLS];
  int b = blockIdx.x / NBLK;
  int blkInB = blockIdx.x % NBLK;
  int pix0 = blkInB * 512;
  int tid = threadIdx.x;
  if (tid < NCLS) { sLab[tid] = cls_label[b * NCLS + tid]; sCnt[tid] = 0; }
  int wave = tid >> 6, lane = tid & 63;
  const float* camb = cam + (size_t)b * NCLS * HW + pix0;

  // ---- stage: 10 independent coalesced float4 loads per lane ----
  float4 r[10];
#pragma unroll
  for (int k = 0; k < 10; ++k) {
    int c = wave * 5 + (k >> 1);
    int off = (k & 1) * 256 + lane * 4;
    r[k] = *(const float4*)(camb + (size_t)c * HW + off);
  }
#pragma unroll
  for (int k = 0; k < 10; ++k) {
    int c = wave * 5 + (k >> 1);
    int off = (k & 1) * 256 + lane * 4;
    *(float4*)&sT[c][off] = r[k];
  }
  __syncthreads();

  // ---- consume: branchless top-2 + candidate mask (2 px/thread) ----
  float top1[2] = {-1.0f, -1.0f}, sec[2] = {-1.0f, -1.0f};
  int idx1[2] = {0, 0};
  unsigned cm[2] = {0u, 0u};
#pragma unroll
  for (int c = 0; c < NCLS; ++c) {
    float lab = sLab[c];
    float2 t2 = *(const float2*)&sT[c][tid * 2];
    float vv[2] = {t2.x * lab, t2.y * lab};
#pragma unroll
    for (int u = 0; u < 2; ++u) {
      float x = vv[u];
      // ascending c + strict '>' == lowest-index tie-break (JAX top_k)
      bool gt = x > top1[u];
      sec[u] = gt ? top1[u] : fmaxf(sec[u], fminf(x, top1[u]));
      idx1[u] = gt ? c : idx1[u];
      top1[u] = gt ? x : top1[u];
      cm[u] |= (x >= TFILT) ? (1u << c) : 0u;
    }
  }

  // ---- rare side effects (LDS-atomic slot reserve; no global return-atomics) ----
  float hig = hig_p[0], low = low_p[0], bg = bg_p[0];
#pragma unroll
  for (int u = 0; u < 2; ++u) {
    unsigned m = cm[u];
    while (m) {
      int c = __builtin_ctz(m); m &= m - 1u;
      int pos = atomicAdd(&sCnt[c], 1);
      if (pos < CAPB)
        candIdx[(size_t)((b * NCLS + c) * NBLK + blkInB) * CAPB + pos] = pix0 + tid * 2 + u;
    }
    int ps = idx1[u] + 1;
    float t1 = top1[u];
    if (t1 < hig) ps = 255;
    if (t1 < low) ps = 0;
    if (t1 < bg)  ps = 0;
    if ((t1 - sec[u] < 0.3f) && (t1 > hig)) ps = 255;
    if (ps >= 1 && ps <= NCLS) {
      int cls = ps - 1;
      int pix = pix0 + tid * 2 + u;
      int y = pix / IMG_W, x = pix % IMG_W;
      float sy = (y + 0.5f) * 0.0625f - 0.5f; sy = fminf(fmaxf(sy, 0.0f), 27.0f);
      float sx = (x + 0.5f) * 0.0625f - 0.5f; sx = fminf(fmaxf(sx, 0.0f), 27.0f);
      int fy0 = (int)sy, fx0 = (int)sx;
      int fy1 = min(fy0 + 1, 27), fx1 = min(fx0 + 1, 27);
      float wy = sy - (float)fy0, wx = sx - (float)fx0;
      float* Wb = W + (size_t)(b * NCLS + cls) * 784;
      atomicAdd(&Wb[fy0 * 28 + fx0], (1.0f - wy) * (1.0f - wx));
      atomicAdd(&Wb[fy0 * 28 + fx1], (1.0f - wy) * wx);
      atomicAdd(&Wb[fy1 * 28 + fx0], wy * (1.0f - wx));
      atomicAdd(&Wb[fy1 * 28 + fx1], wy * wx);
      atomicAdd(&counts[b * NCLS + cls], 1);
    }
  }
  __syncthreads();
  if (tid < NCLS)
    cntBlk[(b * NCLS + tid) * NBLK + blkInB] = sCnt[tid];
}

// ---------------------------------------------------------------------------
// K2: per-(b,c) features. 40 blocks x 1024 threads; fmapT dot (coalesced dims).
__global__ __launch_bounds__(1024) void k_features(const float* __restrict__ fmapT,
                                                   const float* __restrict__ cam,
                                                   const float* __restrict__ Wg,
                                                   const int* __restrict__ counts,
                                                   const int* __restrict__ cntBlk,
                                                   const int* __restrict__ candIdx,
                                                   const float* __restrict__ cls_label,
                                                   float* __restrict__ fsm_g) {
  __shared__ float sW[784];
  __shared__ float sPart[4][256];
  __shared__ float cv[CAPG]; __shared__ int ci[CAPG];
  __shared__ float wv[16]; __shared__ int wi[16];
  __shared__ float selV; __shared__ int selI;
  __shared__ int sTop[25];
  __shared__ int sN, sFb;
  int bc = blockIdx.x;
  int b = bc / NCLS;
  int tid = threadIdx.x;
  int dim = tid & 255, part = tid >> 8;
  if (cls_label[bc] == 0.0f) {
    if (tid < 256) fsm_g[(size_t)bc * 256 + tid] = 0.0f;
    return;
  }
  int cnt = counts[bc];
  const float* fT = fmapT + (size_t)b * 784 * 256;
  float res = 0.0f;
  if (cnt > 0) {
    for (int s = tid; s < 784; s += 1024) sW[s] = Wg[(size_t)bc * 784 + s];
    __syncthreads();
    float a0 = 0.0f, a1 = 0.0f, a2 = 0.0f, a3 = 0.0f;
    int s0 = part * 196;
    for (int s = s0; s < s0 + 196; s += 4) {
      a0 += sW[s]     * fT[(size_t)(s)     * 256 + dim];
      a1 += sW[s + 1] * fT[(size_t)(s + 1) * 256 + dim];
      a2 += sW[s + 2] * fT[(size_t)(s + 2) * 256 + dim];
      a3 += sW[s + 3] * fT[(size_t)(s + 3) * 256 + dim];
    }
    sPart[part][dim] = (a0 + a1) + (a2 + a3);
    __syncthreads();
    if (tid < 256)
      res = ((sPart[0][tid] + sPart[1][tid]) + (sPart[2][tid] + sPart[3][tid]))
            / fmaxf((float)cnt, 1.0f);
  } else {
    // ---- exact top-25 (JAX tie-break) from per-block candidate lists ----
    if (tid == 0) { sN = 0; sFb = 0; }
    __syncthreads();
    const float* camc = cam + (size_t)bc * HW;
    if (tid < NBLK) {
      int cb = cntBlk[(size_t)bc * NBLK + tid];
      if (cb > CAPB) sFb = 1;
      else if (cb > 0) {
        int base = atomicAdd(&sN, cb);
        for (int j = 0; j < cb; ++j) {
          int p = base + j;
          if (p < CAPG) ci[p] = candIdx[(size_t)((size_t)bc * NBLK + tid) * CAPB + j];
        }
      }
    }
    __syncthreads();
    int n = sN;
    bool fb = sFb || (n < 25) || (n > CAPG);
    if (!fb) for (int p = tid; p < n; p += 1024) cv[p] = camc[ci[p]];
    __syncthreads();
    float lastV = 3.0e38f; int lastI = -1;
    for (int r = 0; r < 25; ++r) {
      float bv = -1.0e30f; int bi = 0x7fffffff;
      if (!fb) {
        for (int p = tid; p < n; p += 1024) {
          float vv2 = cv[p]; int ii = ci[p];
          if (((vv2 < lastV) || (vv2 == lastV && ii > lastI)) &&
              ((vv2 > bv) || (vv2 == bv && ii < bi))) { bv = vv2; bi = ii; }
        }
      } else {
        for (int p = tid; p < HW; p += 1024) {
          float vv2 = camc[p];
          if (((vv2 < lastV) || (vv2 == lastV && p > lastI)) &&
              ((vv2 > bv) || (vv2 == bv && p < bi))) { bv = vv2; bi = p; }
        }
      }
      for (int off = 32; off > 0; off >>= 1) {
        float ov = __shfl_xor(bv, off, 64);
        int   oi = __shfl_xor(bi, off, 64);
        if (ov > bv || (ov == bv && oi < bi)) { bv = ov; bi = oi; }
      }
      if ((tid & 63) == 0) { wv[tid >> 6] = bv; wi[tid >> 6] = bi; }
      __syncthreads();
      if (tid == 0) {
        for (int w = 1; w < 16; ++w)
          if (wv[w] > bv || (wv[w] == bv && wi[w] < bi)) { bv = wv[w]; bi = wi[w]; }
        selV = bv; selI = bi; sTop[r] = bi;
      }
      __syncthreads();
      lastV = selV; lastI = selI;
    }
    float at = 0.0f;
    for (int r = part; r < 25; r += 4) {
      int p = sTop[r];
      int y = p / IMG_W, x = p % IMG_W;
      float sy = (y + 0.5f) * 0.0625f - 0.5f; sy = fminf(fmaxf(sy, 0.0f), 27.0f);
      float sx = (x + 0.5f) * 0.0625f - 0.5f; sx = fminf(fmaxf(sx, 0.0f), 27.0f);
      int fy0 = (int)sy, fx0 = (int)sx;
      int fy1 = min(fy0 + 1, 27), fx1 = min(fx0 + 1, 27);
      float wy = sy - (float)fy0, wx = sx - (float)fx0;
      at += (1.0f - wy) * (1.0f - wx) * fT[(size_t)(fy0 * 28 + fx0) * 256 + dim]
          + (1.0f - wy) * wx          * fT[(size_t)(fy0 * 28 + fx1) * 256 + dim]
          + wy          * (1.0f - wx) * fT[(size_t)(fy1 * 28 + fx0) * 256 + dim]
          + wy          * wx          * fT[(size_t)(fy1 * 28 + fx1) * 256 + dim];
    }
    sPart[part][dim] = at;
    __syncthreads();
    if (tid < 256)
      res = ((sPart[0][tid] + sPart[1][tid]) + (sPart[2][tid] + sPart[3][tid])) * (1.0f / 25.0f);
  }
  if (tid < 256) fsm_g[(size_t)bc * 256 + tid] = res;
}

// ---------------------------------------------------------------------------
// K3: sequential loss. 512 threads; float2 LDS dots; exact zero-row skip
// (skipped dots are exactly 0.0 -> identical bits through the epilogue).
__global__ __launch_bounds__(512) void k_loss(const float* __restrict__ fsm_g,
                                              const float* __restrict__ cls_label,
                                              const float* __restrict__ proj_w,
                                              const float* __restrict__ fc_init,
                                              float* __restrict__ out) {
  __shared__ float sFsm[NCLS * LK], sFc[NCLS * LK], sPw[NCLS * LK];
  __shared__ float sMat[NCLS * NCLS], sRow[NCLS], sNormI[NCLS], sNormC[NCLS];
  __shared__ int   sZI[NCLS], sZC[NCLS], sQual[NCLS];
  __shared__ float sPres[2][NCLS];
  __shared__ float sScal[2];
  int tid = threadIdx.x;
  if (tid < 256) {
    for (int r = 0; r < NCLS; ++r) {
      sFc[r * LK + tid] = fc_init[r * 256 + tid];
      sPw[r * LK + tid] = proj_w[r * 256 + tid];
    }
  }
  if (tid < 40) sPres[tid / NCLS][tid % NCLS] = cls_label[tid];
  if (tid == 0) { sScal[0] = 0.0f; sScal[1] = 0.0f; }
  __syncthreads();

  for (int b = 0; b < 2; ++b) {
    if (tid < 256)
      for (int r = 0; r < NCLS; ++r) sFsm[r * LK + tid] = fsm_g[(b * NCLS + r) * 256 + tid];
    __syncthreads();
    if (tid < NCLS) {
      float s = 0.0f, t2 = 0.0f;
      for (int d = 0; d < 256; d += 2) {
        float2 a = *(const float2*)&sFsm[tid * LK + d];
        s += a.x * a.x; s += a.y * a.y;
        float2 f = *(const float2*)&sFc[tid * LK + d];
        t2 += f.x * f.x; t2 += f.y * f.y;
      }
      sNormI[tid] = fmaxf(sqrtf(s), 1e-12f);
      sNormC[tid] = fmaxf(sqrtf(t2), 1e-12f);
      sZI[tid] = (s == 0.0f) ? 1 : 0;
      sZC[tid] = (t2 == 0.0f) ? 1 : 0;
    }
    __syncthreads();
    for (int pi = tid; pi < 400; pi += 512) {
      int i = pi / NCLS, j = pi % NCLS;
      float c0;
      if (sZI[i] || sZC[j]) c0 = 0.0f;     // exact: dot of a zero row is 0
      else {
        float acc = 0.0f;
        for (int d = 0; d < 256; d += 2) {
          float2 a = *(const float2*)&sFsm[i * LK + d];
          float2 f = *(const float2*)&sFc[j * LK + d];
          acc += a.x * f.x; acc += a.y * f.y;
        }
        c0 = fabsf(acc / (sNormI[i] * sNormC[j]));
      }
      sMat[pi] = fminf(fmaxf(c0, 1e-5f), 1.0f - 1e-5f);
    }
    __syncthreads();
    if (tid < NCLS) {
      float pres = (sPres[b][tid] > 0.5f) ? 1.0f : 0.0f;
      float rs = 0.0f, om = -3.0e38f;
      for (int j = 0; j < NCLS; ++j) {
        float c0 = sMat[tid * NCLS + j];
        float ident = (tid == j) ? pres : 0.0f;
        rs += ident * logf(c0) + (1.0f - ident) * log1pf(-c0);
        if (j != tid) om = fmaxf(om, c0);
      }
      sRow[tid] = rs;
      sQual[tid] = (pres > 0.5f && om < 0.6f) ? 1 : 0;
    }
    __syncthreads();
    if (tid == 0) {
      float s = 0.0f;
      for (int r = 0; r < NCLS; ++r) s += sRow[r];
      sScal[0] -= s / 400.0f;
    }
    __syncthreads();
    for (int pi = tid; pi < 400; pi += 512) {
      int i = pi / NCLS, j = pi % NCLS;
      float acc = 0.0f;
      if (!sZI[i]) {                        // exact: zero fsm row -> logits 0
        for (int d = 0; d < 256; d += 2) {
          float2 a = *(const float2*)&sFsm[i * LK + d];
          float2 f = *(const float2*)&sPw[j * LK + d];
          acc += a.x * f.x; acc += a.y * f.y;
        }
      }
      sMat[pi] = acc;
    }
    __syncthreads();
    if (tid < NCLS) {
      float m = -3.0e38f;
      for (int j = 0; j < NCLS; ++j) m = fmaxf(m, sMat[tid * NCLS + j]);
      float S = 0.0f;
      for (int j = 0; j < NCLS; ++j) S += expf(sMat[tid * NCLS + j] - m);
      float ts = 0.0f;
      for (int j = 0; j < NCLS; ++j) {
        float p = expf(sMat[tid * NCLS + j] - m) / S;
        if (j == tid) ts += fmaxf(logf(p), -100.0f);
        else          ts += fmaxf(log1pf(-p), -100.0f);
      }
      sRow[tid] = -ts / 20.0f;
    }
    __syncthreads();
    if (tid == 0) {
      float add = 0.0f; int nq = 0;
      for (int r = 0; r < NCLS; ++r) if (sQual[r]) { add += sRow[r]; nq++; }
      float lc = sScal[1] + add;
      if (nq > 0) lc = lc / fmaxf((float)nq, 1.0f);
      sScal[1] = lc;
    }
    __syncthreads();
    if (tid < 256) {
      for (int r = 0; r < NCLS; ++r)
        if (sQual[r]) sFc[r * LK + tid] = 0.95f * sFc[r * LK + tid] + 0.05f * sFsm[r * LK + tid];
    }
    __syncthreads();
  }
  if (tid == 0) out[0] = sScal[0] + sScal[1];
}

// ---------------------------------------------------------------------------
extern "C" void kernel_launch(void* const* d_in, const int* in_sizes, int n_in,
                              void* d_out, int out_size, void* d_ws, size_t ws_size,
                              hipStream_t stream) {
  const float* fmap      = (const float*)d_in[0];
  const float* cam       = (const float*)d_in[1];
  const float* cls_label = (const float*)d_in[2];
  const float* proj_w    = (const float*)d_in[3];
  const float* fc_init   = (const float*)d_in[4];
  const float* hig       = (const float*)d_in[5];
  const float* low       = (const float*)d_in[6];
  const float* bg        = (const float*)d_in[7];
  float* out = (float*)d_out;

  char* ws = (char*)d_ws;
  float* W       = (float*)(ws);                 // 125440 B
  int*   counts  = (int*)  (ws + 125440);        // 160 B
  int*   cntBlk  = (int*)  (ws + 125600);        // 62720 B
  int*   candIdx = (int*)  (ws + 188320);        // 752640 B
  float* fsm     = (float*)(ws + 940960);        // 40960 B
  float* fmapT   = (float*)(ws + 981920);        // 1605632 B  (total 2587552)

  hipMemsetAsync(ws, 0, 125600, stream);         // zero W + counts
  k_transpose    <<< 400,  256, 0, stream>>>(fmap, fmapT);
  k_pseudo_filter<<< 2 * NBLK, 256, 0, stream>>>(cam, cls_label, hig, low, bg,
                                                 W, counts, cntBlk, candIdx);
  k_features     <<<  40, 1024, 0, stream>>>(fmapT, cam, W, counts, cntBlk, candIdx,
                                             cls_label, fsm);
  k_loss         <<<   1,  512, 0, stream>>>(fsm, cls_label, proj_w, fc_init, out);
}

// Round 7
// 179.840 us; speedup vs baseline: 2.2912x; 1.1652x over previous
//
#include <hip/hip_runtime.h>
#include <cstdint>

#define HW 200704      // 448*448
#define IMG_W 448
#define NCLS 20
#define NDIM 256
#define NBLK 392       // cam blocks per batch (512 px each)
#define CAPB 12        // per-(class,block) candidate slots; mean 5.12
#define CAPG 2560      // global candidate cap per (b,c); mean 2016
#define TFILT 0.99f
#define LK 260         // padded LDS stride: float4-aligned, 260%32==4

// ---------------------------------------------------------------------------
// K0: coalesced transpose fmap [B,256,784] -> fmapT [B,784,256] via LDS tiles.
__global__ __launch_bounds__(256) void k_transpose(const float* __restrict__ fmap,
                                                   float* __restrict__ fmapT) {
  __shared__ float tile[32][33];
  int blk = blockIdx.x;
  int b = blk / 200;
  int t = blk % 200;
  int dT = t / 25, sT = t % 25;
  int ty = threadIdx.x >> 5;
  int tx = threadIdx.x & 31;
#pragma unroll
  for (int r = 0; r < 4; ++r) {
    int d = dT * 32 + ty + r * 8;
    int s = sT * 32 + tx;
    if (s < 784) tile[ty + r * 8][tx] = fmap[((size_t)(b * 256 + d)) * 784 + s];
  }
  __syncthreads();
#pragma unroll
  for (int r = 0; r < 4; ++r) {
    int s = sT * 32 + ty + r * 8;
    int d = dT * 32 + tx;
    if (s < 784) fmapT[((size_t)(b * 784 + s)) * 256 + d] = tile[tx][ty + r * 8];
  }
}

// ---------------------------------------------------------------------------
// K1: fused pseudo-label + weight scatter + candidate filter (unchanged r6).
__global__ __launch_bounds__(256) void k_pseudo_filter(const float* __restrict__ cam,
                                                       const float* __restrict__ cls_label,
                                                       const float* __restrict__ hig_p,
                                                       const float* __restrict__ low_p,
                                                       const float* __restrict__ bg_p,
                                                       float* __restrict__ W,
                                                       int* __restrict__ counts,
                                                       int* __restrict__ cntBlk,
                                                       int* __restrict__ candIdx) {
  __shared__ float sT[NCLS][512];      // 40 KB tile
  __shared__ float sLab[NCLS];
  __shared__ int sCnt[NCLS];
  int b = blockIdx.x / NBLK;
  int blkInB = blockIdx.x % NBLK;
  int pix0 = blkInB * 512;
  int tid = threadIdx.x;
  if (tid < NCLS) { sLab[tid] = cls_label[b * NCLS + tid]; sCnt[tid] = 0; }
  int wave = tid >> 6, lane = tid & 63;
  const float* camb = cam + (size_t)b * NCLS * HW + pix0;

  float4 r[10];
#pragma unroll
  for (int k = 0; k < 10; ++k) {
    int c = wave * 5 + (k >> 1);
    int off = (k & 1) * 256 + lane * 4;
    r[k] = *(const float4*)(camb + (size_t)c * HW + off);
  }
#pragma unroll
  for (int k = 0; k < 10; ++k) {
    int c = wave * 5 + (k >> 1);
    int off = (k & 1) * 256 + lane * 4;
    *(float4*)&sT[c][off] = r[k];
  }
  __syncthreads();

  float top1[2] = {-1.0f, -1.0f}, sec[2] = {-1.0f, -1.0f};
  int idx1[2] = {0, 0};
  unsigned cm[2] = {0u, 0u};
#pragma unroll
  for (int c = 0; c < NCLS; ++c) {
    float lab = sLab[c];
    float2 t2 = *(const float2*)&sT[c][tid * 2];
    float vv[2] = {t2.x * lab, t2.y * lab};
#pragma unroll
    for (int u = 0; u < 2; ++u) {
      float x = vv[u];
      bool gt = x > top1[u];
      sec[u] = gt ? top1[u] : fmaxf(sec[u], fminf(x, top1[u]));
      idx1[u] = gt ? c : idx1[u];
      top1[u] = gt ? x : top1[u];
      cm[u] |= (x >= TFILT) ? (1u << c) : 0u;
    }
  }

  float hig = hig_p[0], low = low_p[0], bg = bg_p[0];
#pragma unroll
  for (int u = 0; u < 2; ++u) {
    unsigned m = cm[u];
    while (m) {
      int c = __builtin_ctz(m); m &= m - 1u;
      int pos = atomicAdd(&sCnt[c], 1);
      if (pos < CAPB)
        candIdx[(size_t)((b * NCLS + c) * NBLK + blkInB) * CAPB + pos] = pix0 + tid * 2 + u;
    }
    int ps = idx1[u] + 1;
    float t1 = top1[u];
    if (t1 < hig) ps = 255;
    if (t1 < low) ps = 0;
    if (t1 < bg)  ps = 0;
    if ((t1 - sec[u] < 0.3f) && (t1 > hig)) ps = 255;
    if (ps >= 1 && ps <= NCLS) {
      int cls = ps - 1;
      int pix = pix0 + tid * 2 + u;
      int y = pix / IMG_W, x = pix % IMG_W;
      float sy = (y + 0.5f) * 0.0625f - 0.5f; sy = fminf(fmaxf(sy, 0.0f), 27.0f);
      float sx = (x + 0.5f) * 0.0625f - 0.5f; sx = fminf(fmaxf(sx, 0.0f), 27.0f);
      int fy0 = (int)sy, fx0 = (int)sx;
      int fy1 = min(fy0 + 1, 27), fx1 = min(fx0 + 1, 27);
      float wy = sy - (float)fy0, wx = sx - (float)fx0;
      float* Wb = W + (size_t)(b * NCLS + cls) * 784;
      atomicAdd(&Wb[fy0 * 28 + fx0], (1.0f - wy) * (1.0f - wx));
      atomicAdd(&Wb[fy0 * 28 + fx1], (1.0f - wy) * wx);
      atomicAdd(&Wb[fy1 * 28 + fx0], wy * (1.0f - wx));
      atomicAdd(&Wb[fy1 * 28 + fx1], wy * wx);
      atomicAdd(&counts[b * NCLS + cls], 1);
    }
  }
  __syncthreads();
  if (tid < NCLS)
    cntBlk[(b * NCLS + tid) * NBLK + blkInB] = sCnt[tid];
}

// ---------------------------------------------------------------------------
// K2: per-(b,c) features (unchanged r6).
__global__ __launch_bounds__(1024) void k_features(const float* __restrict__ fmapT,
                                                   const float* __restrict__ cam,
                                                   const float* __restrict__ Wg,
                                                   const int* __restrict__ counts,
                                                   const int* __restrict__ cntBlk,
                                                   const int* __restrict__ candIdx,
                                                   const float* __restrict__ cls_label,
                                                   float* __restrict__ fsm_g) {
  __shared__ float sW[784];
  __shared__ float sPart[4][256];
  __shared__ float cv[CAPG]; __shared__ int ci[CAPG];
  __shared__ float wv[16]; __shared__ int wi[16];
  __shared__ float selV; __shared__ int selI;
  __shared__ int sTop[25];
  __shared__ int sN, sFb;
  int bc = blockIdx.x;
  int b = bc / NCLS;
  int tid = threadIdx.x;
  int dim = tid & 255, part = tid >> 8;
  if (cls_label[bc] == 0.0f) {
    if (tid < 256) fsm_g[(size_t)bc * 256 + tid] = 0.0f;
    return;
  }
  int cnt = counts[bc];
  const float* fT = fmapT + (size_t)b * 784 * 256;
  float res = 0.0f;
  if (cnt > 0) {
    for (int s = tid; s < 784; s += 1024) sW[s] = Wg[(size_t)bc * 784 + s];
    __syncthreads();
    float a0 = 0.0f, a1 = 0.0f, a2 = 0.0f, a3 = 0.0f;
    int s0 = part * 196;
    for (int s = s0; s < s0 + 196; s += 4) {
      a0 += sW[s]     * fT[(size_t)(s)     * 256 + dim];
      a1 += sW[s + 1] * fT[(size_t)(s + 1) * 256 + dim];
      a2 += sW[s + 2] * fT[(size_t)(s + 2) * 256 + dim];
      a3 += sW[s + 3] * fT[(size_t)(s + 3) * 256 + dim];
    }
    sPart[part][dim] = (a0 + a1) + (a2 + a3);
    __syncthreads();
    if (tid < 256)
      res = ((sPart[0][tid] + sPart[1][tid]) + (sPart[2][tid] + sPart[3][tid]))
            / fmaxf((float)cnt, 1.0f);
  } else {
    if (tid == 0) { sN = 0; sFb = 0; }
    __syncthreads();
    const float* camc = cam + (size_t)bc * HW;
    if (tid < NBLK) {
      int cb = cntBlk[(size_t)bc * NBLK + tid];
      if (cb > CAPB) sFb = 1;
      else if (cb > 0) {
        int base = atomicAdd(&sN, cb);
        for (int j = 0; j < cb; ++j) {
          int p = base + j;
          if (p < CAPG) ci[p] = candIdx[(size_t)((size_t)bc * NBLK + tid) * CAPB + j];
        }
      }
    }
    __syncthreads();
    int n = sN;
    bool fb = sFb || (n < 25) || (n > CAPG);
    if (!fb) for (int p = tid; p < n; p += 1024) cv[p] = camc[ci[p]];
    __syncthreads();
    float lastV = 3.0e38f; int lastI = -1;
    for (int r = 0; r < 25; ++r) {
      float bv = -1.0e30f; int bi = 0x7fffffff;
      if (!fb) {
        for (int p = tid; p < n; p += 1024) {
          float vv2 = cv[p]; int ii = ci[p];
          if (((vv2 < lastV) || (vv2 == lastV && ii > lastI)) &&
              ((vv2 > bv) || (vv2 == bv && ii < bi))) { bv = vv2; bi = ii; }
        }
      } else {
        for (int p = tid; p < HW; p += 1024) {
          float vv2 = camc[p];
          if (((vv2 < lastV) || (vv2 == lastV && p > lastI)) &&
              ((vv2 > bv) || (vv2 == bv && p < bi))) { bv = vv2; bi = p; }
        }
      }
      for (int off = 32; off > 0; off >>= 1) {
        float ov = __shfl_xor(bv, off, 64);
        int   oi = __shfl_xor(bi, off, 64);
        if (ov > bv || (ov == bv && oi < bi)) { bv = ov; bi = oi; }
      }
      if ((tid & 63) == 0) { wv[tid >> 6] = bv; wi[tid >> 6] = bi; }
      __syncthreads();
      if (tid == 0) {
        for (int w = 1; w < 16; ++w)
          if (wv[w] > bv || (wv[w] == bv && wi[w] < bi)) { bv = wv[w]; bi = wi[w]; }
        selV = bv; selI = bi; sTop[r] = bi;
      }
      __syncthreads();
      lastV = selV; lastI = selI;
    }
    float at = 0.0f;
    for (int r = part; r < 25; r += 4) {
      int p = sTop[r];
      int y = p / IMG_W, x = p % IMG_W;
      float sy = (y + 0.5f) * 0.0625f - 0.5f; sy = fminf(fmaxf(sy, 0.0f), 27.0f);
      float sx = (x + 0.5f) * 0.0625f - 0.5f; sx = fminf(fmaxf(sx, 0.0f), 27.0f);
      int fy0 = (int)sy, fx0 = (int)sx;
      int fy1 = min(fy0 + 1, 27), fx1 = min(fx0 + 1, 27);
      float wy = sy - (float)fy0, wx = sx - (float)fx0;
      at += (1.0f - wy) * (1.0f - wx) * fT[(size_t)(fy0 * 28 + fx0) * 256 + dim]
          + (1.0f - wy) * wx          * fT[(size_t)(fy0 * 28 + fx1) * 256 + dim]
          + wy          * (1.0f - wx) * fT[(size_t)(fy1 * 28 + fx0) * 256 + dim]
          + wy          * wx          * fT[(size_t)(fy1 * 28 + fx1) * 256 + dim];
    }
    sPart[part][dim] = at;
    __syncthreads();
    if (tid < 256)
      res = ((sPart[0][tid] + sPart[1][tid]) + (sPart[2][tid] + sPart[3][tid])) * (1.0f / 25.0f);
  }
  if (tid < 256) fsm_g[(size_t)bc * 256 + tid] = res;
}

// ---------------------------------------------------------------------------
// K3: sequential loss, ILP-restructured. 1024 threads:
//  - dots: 2 lanes/pair, float4 LDS reads, 4 accumulators (chain 128->16)
//  - norms: 40 rows x 8-lane teams, shuffle reduce (zero-detect exact)
//  - row phases: 20 rows x 32-lane teams, one transcendental per lane
__global__ __launch_bounds__(1024) void k_loss(const float* __restrict__ fsm_g,
                                               const float* __restrict__ cls_label,
                                               const float* __restrict__ proj_w,
                                               const float* __restrict__ fc_init,
                                               float* __restrict__ out) {
  __shared__ float sFsm[NCLS * LK], sFc[NCLS * LK], sPw[NCLS * LK];
  __shared__ float sMat[NCLS * NCLS], sRow[NCLS], sNormI[NCLS], sNormC[NCLS];
  __shared__ int   sZI[NCLS], sZC[NCLS], sQual[NCLS];
  __shared__ float sPres[2][NCLS];
  __shared__ float sScal[2];
  int tid = threadIdx.x;
  for (int idx = tid; idx < NCLS * NDIM; idx += 1024) {
    int r = idx >> 8, d = idx & 255;
    sFc[r * LK + d] = fc_init[idx];
    sPw[r * LK + d] = proj_w[idx];
  }
  if (tid < 40) sPres[tid / NCLS][tid % NCLS] = cls_label[tid];
  if (tid == 0) { sScal[0] = 0.0f; sScal[1] = 0.0f; }
  __syncthreads();

  for (int b = 0; b < 2; ++b) {
    for (int idx = tid; idx < NCLS * NDIM; idx += 1024)
      sFsm[(idx >> 8) * LK + (idx & 255)] = fsm_g[b * NCLS * NDIM + idx];
    __syncthreads();

    // ---- norms: 40 rows x 8 lanes ----
    {
      int g = tid >> 3, sub = tid & 7;
      if (g < 40) {
        const float* row = (g < NCLS) ? &sFsm[g * LK] : &sFc[(g - NCLS) * LK];
        float a0 = 0.0f, a1 = 0.0f, a2 = 0.0f, a3 = 0.0f;
        int d0 = sub * 32;
#pragma unroll
        for (int d = d0; d < d0 + 32; d += 8) {
          float4 x = *(const float4*)&row[d];
          float4 y = *(const float4*)&row[d + 4];
          a0 += x.x * x.x + x.y * x.y;
          a1 += x.z * x.z + x.w * x.w;
          a2 += y.x * y.x + y.y * y.y;
          a3 += y.z * y.z + y.w * y.w;
        }
        float s = (a0 + a1) + (a2 + a3);
        s += __shfl_xor(s, 1, 64);
        s += __shfl_xor(s, 2, 64);
        s += __shfl_xor(s, 4, 64);
        if (sub == 0) {
          if (g < NCLS) { sNormI[g] = fmaxf(sqrtf(s), 1e-12f); sZI[g] = (s == 0.0f); }
          else { sNormC[g - NCLS] = fmaxf(sqrtf(s), 1e-12f); sZC[g - NCLS] = (s == 0.0f); }
        }
      }
    }
    __syncthreads();

    // ---- cos dots: 400 pairs x 2 lanes ----
    {
      int pair = tid >> 1, sub = tid & 1;
      if (pair < 400) {
        int i = pair / NCLS, j = pair % NCLS;
        float c0;
        if (sZI[i] || sZC[j]) c0 = 0.0f;     // exact: dot with zero row is 0
        else {
          const float* ra = &sFsm[i * LK];
          const float* rb = &sFc[j * LK];
          float a0 = 0.0f, a1 = 0.0f, a2 = 0.0f, a3 = 0.0f;
          int d0 = sub * 128;
          for (int d = d0; d < d0 + 128; d += 8) {
            float4 x  = *(const float4*)&ra[d];
            float4 y  = *(const float4*)&rb[d];
            float4 x2 = *(const float4*)&ra[d + 4];
            float4 y2 = *(const float4*)&rb[d + 4];
            a0 += x.x * y.x + x.y * y.y;
            a1 += x.z * y.z + x.w * y.w;
            a2 += x2.x * y2.x + x2.y * y2.y;
            a3 += x2.z * y2.z + x2.w * y2.w;
          }
          float acc = (a0 + a1) + (a2 + a3);
          acc += __shfl_xor(acc, 1, 64);
          c0 = fabsf(acc / (sNormI[i] * sNormC[j]));
        }
        if (sub == 0) sMat[pair] = fminf(fmaxf(c0, 1e-5f), 1.0f - 1e-5f);
      }
    }
    __syncthreads();

    // ---- row loss + qualify: 20 rows x 32 lanes ----
    {
      int i = tid >> 5, jj = tid & 31;
      if (i < NCLS) {
        float pres = (sPres[b][i] > 0.5f) ? 1.0f : 0.0f;
        float contrib = 0.0f, omv = -3.0e38f;
        if (jj < NCLS) {
          float c0 = sMat[i * NCLS + jj];
          float ident = (jj == i) ? pres : 0.0f;
          contrib = ident * logf(c0) + (1.0f - ident) * log1pf(-c0);
          if (jj != i) omv = c0;
        }
#pragma unroll
        for (int off = 1; off < 32; off <<= 1) {
          contrib += __shfl_xor(contrib, off, 64);
          omv = fmaxf(omv, __shfl_xor(omv, off, 64));
        }
        if (jj == 0) { sRow[i] = contrib; sQual[i] = (pres > 0.5f && omv < 0.6f) ? 1 : 0; }
      }
    }
    __syncthreads();
    if (tid == 0) {
      float s = 0.0f;
      for (int r = 0; r < NCLS; ++r) s += sRow[r];
      sScal[0] -= s / 400.0f;
    }
    __syncthreads();

    // ---- logits: 400 pairs x 2 lanes ----
    {
      int pair = tid >> 1, sub = tid & 1;
      if (pair < 400) {
        int i = pair / NCLS, j = pair % NCLS;
        float acc = 0.0f;
        if (!sZI[i]) {                        // exact: zero fsm row -> logits 0
          const float* ra = &sFsm[i * LK];
          const float* rb = &sPw[j * LK];
          float a0 = 0.0f, a1 = 0.0f, a2 = 0.0f, a3 = 0.0f;
          int d0 = sub * 128;
          for (int d = d0; d < d0 + 128; d += 8) {
            float4 x  = *(const float4*)&ra[d];
            float4 y  = *(const float4*)&rb[d];
            float4 x2 = *(const float4*)&ra[d + 4];
            float4 y2 = *(const float4*)&rb[d + 4];
            a0 += x.x * y.x + x.y * y.y;
            a1 += x.z * y.z + x.w * y.w;
            a2 += x2.x * y2.x + x2.y * y2.y;
            a3 += x2.z * y2.z + x2.w * y2.w;
          }
          acc = (a0 + a1) + (a2 + a3);
          acc += __shfl_xor(acc, 1, 64);
        }
        if (sub == 0) sMat[pair] = acc;
      }
    }
    __syncthreads();

    // ---- softmax BCE per row: 20 rows x 32 lanes ----
    {
      int i = tid >> 5, jj = tid & 31;
      if (i < NCLS) {
        float l = (jj < NCLS) ? sMat[i * NCLS + jj] : -3.0e38f;
        float m = l;
#pragma unroll
        for (int off = 1; off < 32; off <<= 1) m = fmaxf(m, __shfl_xor(m, off, 64));
        float e = (jj < NCLS) ? expf(l - m) : 0.0f;
        float S = e;
#pragma unroll
        for (int off = 1; off < 32; off <<= 1) S += __shfl_xor(S, off, 64);
        float term = 0.0f;
        if (jj < NCLS) {
          float p = e / S;
          term = (jj == i) ? fmaxf(logf(p), -100.0f) : fmaxf(log1pf(-p), -100.0f);
        }
#pragma unroll
        for (int off = 1; off < 32; off <<= 1) term += __shfl_xor(term, off, 64);
        if (jj == 0) sRow[i] = -term / 20.0f;
      }
    }
    __syncthreads();
    if (tid == 0) {
      float add = 0.0f; int nq = 0;
      for (int r = 0; r < NCLS; ++r) if (sQual[r]) { add += sRow[r]; nq++; }
      float lc = sScal[1] + add;
      if (nq > 0) lc = lc / fmaxf((float)nq, 1.0f);
      sScal[1] = lc;
    }
    // ---- EMA (same region: disjoint from sRow/sQual reads above) ----
    for (int idx = tid; idx < NCLS * NDIM; idx += 1024) {
      int r = idx >> 8, d = idx & 255;
      if (sQual[r]) sFc[r * LK + d] = 0.95f * sFc[r * LK + d] + 0.05f * sFsm[r * LK + d];
    }
    __syncthreads();
  }
  if (tid == 0) out[0] = sScal[0] + sScal[1];
}

// ---------------------------------------------------------------------------
extern "C" void kernel_launch(void* const* d_in, const int* in_sizes, int n_in,
                              void* d_out, int out_size, void* d_ws, size_t ws_size,
                              hipStream_t stream) {
  const float* fmap      = (const float*)d_in[0];
  const float* cam       = (const float*)d_in[1];
  const float* cls_label = (const float*)d_in[2];
  const float* proj_w    = (const float*)d_in[3];
  const float* fc_init   = (const float*)d_in[4];
  const float* hig       = (const float*)d_in[5];
  const float* low       = (const float*)d_in[6];
  const float* bg        = (const float*)d_in[7];
  float* out = (float*)d_out;

  char* ws = (char*)d_ws;
  float* W       = (float*)(ws);                 // 125440 B
  int*   counts  = (int*)  (ws + 125440);        // 160 B
  int*   cntBlk  = (int*)  (ws + 125600);        // 62720 B
  int*   candIdx = (int*)  (ws + 188320);        // 752640 B
  float* fsm     = (float*)(ws + 940960);        // 40960 B
  float* fmapT   = (float*)(ws + 981920);        // 1605632 B

  hipMemsetAsync(ws, 0, 125600, stream);         // zero W + counts
  k_transpose    <<< 400,  256, 0, stream>>>(fmap, fmapT);
  k_pseudo_filter<<< 2 * NBLK, 256, 0, stream>>>(cam, cls_label, hig, low, bg,
                                                 W, counts, cntBlk, candIdx);
  k_features     <<<  40, 1024, 0, stream>>>(fmapT, cam, W, counts, cntBlk, candIdx,
                                             cls_label, fsm);
  k_loss         <<<   1, 1024, 0, stream>>>(fsm, cls_label, proj_w, fc_init, out);
}